// Round 4
// baseline (1206.076 us; speedup 1.0000x reference)
//
#include <hip/hip_runtime.h>
#include <hip/hip_bf16.h>

#define T_SEQ 2048
#define CDIM 512
#define HDIM 8
#define DHEAD 64
#define BT 4096   // B*T
#define CHUNK 256 // j-rows per wave in attn

// ---------------------------------------------------------------------------
// Kernel 1: elementwise tanh of x and the three weight matrices
// ---------------------------------------------------------------------------
__global__ __launch_bounds__(256) void tanh_prep(
    const float* __restrict__ x,  const float* __restrict__ wq,
    const float* __restrict__ wk, const float* __restrict__ wv,
    float* __restrict__ xact, float* __restrict__ wqa,
    float* __restrict__ wka,  float* __restrict__ wva)
{
    const int NX = BT * CDIM / 4;     // 524288 float4
    const int NW = CDIM * CDIM / 4;   // 65536 float4
    int idx = blockIdx.x * 256 + threadIdx.x;
    const float4* src; float4* dst; int off;
    if (idx < NX)           { src = (const float4*)x;  dst = (float4*)xact; off = idx; }
    else if (idx < NX+NW)   { src = (const float4*)wq; dst = (float4*)wqa;  off = idx - NX; }
    else if (idx < NX+2*NW) { src = (const float4*)wk; dst = (float4*)wka;  off = idx - NX - NW; }
    else                    { src = (const float4*)wv; dst = (float4*)wva;  off = idx - NX - 2*NW; }
    float4 t = src[off];
    t.x = tanhf(t.x); t.y = tanhf(t.y); t.z = tanhf(t.z); t.w = tanhf(t.w);
    dst[off] = t;
}

// ---------------------------------------------------------------------------
// Kernel 2: L1-cdist projection (R2 structure: 64x64 tile, 4x4 micro-tile,
// stride-16 micro rows -> 2-way LDS conflicts only).
// ---------------------------------------------------------------------------
#define PSTR 36
__global__ __launch_bounds__(256) void proj_l1(
    const float* __restrict__ xact,
    const float* __restrict__ wqa, const float* __restrict__ wka, const float* __restrict__ wva,
    const float* __restrict__ gq,  const float* __restrict__ gk,  const float* __restrict__ gv,
    float* __restrict__ oq, float* __restrict__ okk, float* __restrict__ ov)
{
    __shared__ float As[64][PSTR];
    __shared__ float Bs[64][PSTR];

    const int z = blockIdx.z;
    const float* w    = (z == 0) ? wqa : (z == 1) ? wka : wva;
    const float* gain = (z == 0) ? gq  : (z == 1) ? gk  : gv;
    float* outp       = (z == 0) ? oq  : (z == 1) ? okk : ov;

    const int row0 = blockIdx.y * 64;
    const int col0 = blockIdx.x * 64;
    const int tid = threadIdx.x;
    const int tx = tid & 15, ty = tid >> 4;
    const int lr = tid >> 3;          // 0..31
    const int lc = (tid & 7) * 4;     // 0..28

    float acc[4][4];
    #pragma unroll
    for (int i = 0; i < 4; ++i)
        #pragma unroll
        for (int j = 0; j < 4; ++j) acc[i][j] = 0.f;

    for (int k0 = 0; k0 < CDIM; k0 += 32) {
        float4 a0 = *(const float4*)&xact[(size_t)(row0 + lr)      * CDIM + k0 + lc];
        float4 a1 = *(const float4*)&xact[(size_t)(row0 + lr + 32) * CDIM + k0 + lc];
        float4 b0 = *(const float4*)&w[(size_t)(col0 + lr)      * CDIM + k0 + lc];
        float4 b1 = *(const float4*)&w[(size_t)(col0 + lr + 32) * CDIM + k0 + lc];
        __syncthreads();
        *(float4*)&As[lr][lc]      = a0;
        *(float4*)&As[lr + 32][lc] = a1;
        *(float4*)&Bs[lr][lc]      = b0;
        *(float4*)&Bs[lr + 32][lc] = b1;
        __syncthreads();

        #pragma unroll
        for (int kk = 0; kk < 32; kk += 4) {
            float4 a4[4], b4[4];
            #pragma unroll
            for (int i = 0; i < 4; ++i) a4[i] = *(const float4*)&As[ty + 16*i][kk];
            #pragma unroll
            for (int j = 0; j < 4; ++j) b4[j] = *(const float4*)&Bs[tx + 16*j][kk];
            #pragma unroll
            for (int i = 0; i < 4; ++i)
                #pragma unroll
                for (int j = 0; j < 4; ++j)
                    acc[i][j] += fabsf(a4[i].x - b4[j].x) + fabsf(a4[i].y - b4[j].y)
                               + fabsf(a4[i].z - b4[j].z) + fabsf(a4[i].w - b4[j].w);
        }
    }

    float gcol[4];
    #pragma unroll
    for (int j = 0; j < 4; ++j) gcol[j] = gain[col0 + tx + 16*j];

    #pragma unroll
    for (int i = 0; i < 4; ++i) {
        const int r = row0 + ty + 16*i;
        #pragma unroll
        for (int j = 0; j < 4; ++j) {
            const int c = col0 + tx + 16*j;
            float val = (0.5f - acc[i][j] * (1.0f / 512.0f)) * gcol[j];
            if (z < 2) val = tanhf(val);
            outp[(size_t)r * CDIM + c] = val;
        }
    }
}

// ---------------------------------------------------------------------------
// Kernel 3: causal L1-kernel attention, scalar-broadcast scheme.
// Block = 512 thr (8 waves) = one (strip it, bh). Lane owns q-row i0+lane
// (Q and O fully in registers). Wave w covers j in [256w, 256w+256).
// K/V rows are wave-uniform loads (scalarizable). Partials combined in LDS.
// Grid 512 blocks, largest strips first.
// ---------------------------------------------------------------------------
__global__ __launch_bounds__(512) void attn_l1(
    const float* __restrict__ qg, const float* __restrict__ kg, const float* __restrict__ vg,
    const float* __restrict__ gamma, const float* __restrict__ rho,
    float* __restrict__ ab)
{
    __shared__ float som[64][68];
    __shared__ float ssum[64];

    const int bx = blockIdx.x;
    const int it = 31 - (bx >> 4);      // big strips dispatched first
    const int bh = bx & 15;
    const int b = bh >> 3, h = bh & 7;
    const int i0 = it * 64;

    const int tid = threadIdx.x;
    const int wid = tid >> 6;
    const int lane = tid & 63;

    const float gp = log1pf(__expf(gamma[h]));
    const float rp = log1pf(__expf(rho[h]));
    // den = 1 + 1e-6 + gp*(l1/8)^2 = (1+1e-6) + (gp/64)*l1*l1
    const float gp64 = gp * (1.0f / 64.0f);
    const float mrho = -rp;

    const size_t hb = (size_t)b * T_SEQ * CDIM + h * DHEAD;

    const int jstart = wid * CHUNK;
    const int jend = min(jstart + CHUNK, i0 + 64);
    const bool active = (jstart < jend);

    float4 q[16], o[16];
    float acc_s = 0.f;
    #pragma unroll
    for (int d = 0; d < 16; ++d) o[d] = make_float4(0.f, 0.f, 0.f, 0.f);

    const int r = i0 + lane;   // this lane's q row

    if (active) {
        const float* qr = qg + hb + (size_t)r * CDIM;
        #pragma unroll
        for (int d = 0; d < 16; ++d) q[d] = *(const float4*)(qr + 4*d);

        for (int j = jstart; j < jend; ++j) {
            // ---- L1(q_r, k_j): k_j is wave-uniform ----
            const float* kr = kg + hb + (size_t)j * CDIM;
            float l1a = 0.f, l1b = 0.f, l1c = 0.f, l1d = 0.f;
            #pragma unroll
            for (int d = 0; d < 16; ++d) {
                const float4 kx = *(const float4*)(kr + 4*d);
                l1a += fabsf(q[d].x - kx.x);
                l1b += fabsf(q[d].y - kx.y);
                l1c += fabsf(q[d].z - kx.z);
                l1d += fabsf(q[d].w - kx.w);
            }
            const float l1 = (l1a + l1b) + (l1c + l1d);
            const float den = fmaf(gp64 * l1, l1, 1.0f + 1e-6f);
            float wgt = __builtin_amdgcn_exp2f(mrho * __builtin_amdgcn_logf(den));
            wgt = (j <= r) ? wgt : 0.f;   // causal mask
            acc_s += wgt;

            // ---- O += wgt * v_j (v_j wave-uniform) ----
            const float* vr = vg + hb + (size_t)j * CDIM;
            #pragma unroll
            for (int d = 0; d < 16; ++d) {
                const float4 vx = *(const float4*)(vr + 4*d);
                o[d].x = fmaf(wgt, vx.x, o[d].x);
                o[d].y = fmaf(wgt, vx.y, o[d].y);
                o[d].z = fmaf(wgt, vx.z, o[d].z);
                o[d].w = fmaf(wgt, vx.w, o[d].w);
            }
        }
    }

    // ---- combine the 8 waves' partials through LDS ----
    if (wid == 0) {
        #pragma unroll
        for (int d = 0; d < 16; ++d) *(float4*)&som[lane][4*d] = o[d];
        ssum[lane] = acc_s;
    }
    __syncthreads();
    #pragma unroll
    for (int w = 1; w < 8; ++w) {
        if (wid == w && active) {
            #pragma unroll
            for (int d = 0; d < 16; ++d) {
                float4 cur = *(const float4*)&som[lane][4*d];
                cur.x += o[d].x; cur.y += o[d].y; cur.z += o[d].z; cur.w += o[d].w;
                *(float4*)&som[lane][4*d] = cur;
            }
            ssum[lane] += acc_s;
        }
        __syncthreads();
    }

    // ---- normalize and store (512 threads, 4096 outputs -> 8 each) ----
    const int orow = tid >> 3;
    const int ocol = (tid & 7) * 8;
    const float inv = 1.0f / (ssum[orow] + 1e-6f);
    float4 u0 = *(const float4*)&som[orow][ocol];
    float4 u1 = *(const float4*)&som[orow][ocol + 4];
    u0.x *= inv; u0.y *= inv; u0.z *= inv; u0.w *= inv;
    u1.x *= inv; u1.y *= inv; u1.z *= inv; u1.w *= inv;
    float* op = ab + hb + (size_t)(i0 + orow) * CDIM + ocol;
    *(float4*)op = u0;
    *(float4*)(op + 4) = u1;
}

// ---------------------------------------------------------------------------
// Kernel 4: output projection Y = A @ wo^T + bias. M=4096, N=512, K=512.
// (R2 structure)
// ---------------------------------------------------------------------------
__global__ __launch_bounds__(256) void out_gemm(
    const float* __restrict__ A, const float* __restrict__ wo,
    const float* __restrict__ bias, float* __restrict__ Y)
{
    __shared__ float As[64][PSTR];
    __shared__ float Bs[64][PSTR];

    const int row0 = blockIdx.y * 64;
    const int col0 = blockIdx.x * 64;
    const int tid = threadIdx.x;
    const int tx = tid & 15, ty = tid >> 4;
    const int lr = tid >> 3;
    const int lc = (tid & 7) * 4;

    float acc[4][4];
    #pragma unroll
    for (int i = 0; i < 4; ++i)
        #pragma unroll
        for (int j = 0; j < 4; ++j) acc[i][j] = 0.f;

    for (int k0 = 0; k0 < CDIM; k0 += 32) {
        float4 a0 = *(const float4*)&A[(size_t)(row0 + lr)      * CDIM + k0 + lc];
        float4 a1 = *(const float4*)&A[(size_t)(row0 + lr + 32) * CDIM + k0 + lc];
        float4 b0 = *(const float4*)&wo[(size_t)(col0 + lr)      * CDIM + k0 + lc];
        float4 b1 = *(const float4*)&wo[(size_t)(col0 + lr + 32) * CDIM + k0 + lc];
        __syncthreads();
        *(float4*)&As[lr][lc]      = a0;
        *(float4*)&As[lr + 32][lc] = a1;
        *(float4*)&Bs[lr][lc]      = b0;
        *(float4*)&Bs[lr + 32][lc] = b1;
        __syncthreads();

        #pragma unroll
        for (int kk = 0; kk < 32; kk += 4) {
            float4 a4[4], b4[4];
            #pragma unroll
            for (int i = 0; i < 4; ++i) a4[i] = *(const float4*)&As[ty + 16*i][kk];
            #pragma unroll
            for (int j = 0; j < 4; ++j) b4[j] = *(const float4*)&Bs[tx + 16*j][kk];
            #pragma unroll
            for (int i = 0; i < 4; ++i)
                #pragma unroll
                for (int j = 0; j < 4; ++j)
                    acc[i][j] += a4[i].x * b4[j].x + a4[i].y * b4[j].y
                               + a4[i].z * b4[j].z + a4[i].w * b4[j].w;
        }
    }

    float bcol[4];
    #pragma unroll
    for (int j = 0; j < 4; ++j) bcol[j] = bias[col0 + tx + 16*j];

    #pragma unroll
    for (int i = 0; i < 4; ++i) {
        const int r = row0 + ty + 16*i;
        #pragma unroll
        for (int j = 0; j < 4; ++j) {
            const int c = col0 + tx + 16*j;
            Y[(size_t)r * CDIM + c] = acc[i][j] + bcol[j];
        }
    }
}

// ---------------------------------------------------------------------------
extern "C" void kernel_launch(void* const* d_in, const int* in_sizes, int n_in,
                              void* d_out, int out_size, void* d_ws, size_t ws_size,
                              hipStream_t stream)
{
    (void)in_sizes; (void)n_in; (void)out_size; (void)ws_size;
    const float* x     = (const float*)d_in[0];
    // d_in[1] = mask (causal tril; semantics hardcoded)
    const float* wq    = (const float*)d_in[2];
    const float* gq    = (const float*)d_in[3];
    const float* wk    = (const float*)d_in[4];
    const float* gk    = (const float*)d_in[5];
    const float* wv    = (const float*)d_in[6];
    const float* gv    = (const float*)d_in[7];
    const float* wo    = (const float*)d_in[8];
    const float* wob   = (const float*)d_in[9];
    const float* gamma = (const float*)d_in[10];
    const float* rho   = (const float*)d_in[11];
    float* out = (float*)d_out;

    const size_t NV = (size_t)BT * CDIM;   // 2,097,152 floats
    const size_t NW = (size_t)CDIM * CDIM; //   262,144

    float* ws   = (float*)d_ws;
    float* xact = ws;                 // NV (dead after proj_l1 -> reused as ab)
    float* wqa  = xact + NV;          // NW
    float* wka  = wqa + NW;
    float* wva  = wka + NW;
    float* qb   = wva + NW;           // NV
    float* kb   = qb + NV;
    float* vb   = kb + NV;
    float* ab   = xact;               // alias

    tanh_prep<<<2816, 256, 0, stream>>>(x, wq, wk, wv, xact, wqa, wka, wva);
    proj_l1<<<dim3(8, 64, 3), 256, 0, stream>>>(xact, wqa, wka, wva,
                                                gq, gk, gv, qb, kb, vb);
    attn_l1<<<512, 512, 0, stream>>>(qb, kb, vb, gamma, rho, ab);
    out_gemm<<<dim3(8, 64), 256, 0, stream>>>(ab, wo, wob, out);
}

// Round 6
// 674.278 us; speedup vs baseline: 1.7887x; 1.7887x over previous
//
#include <hip/hip_runtime.h>
#include <hip/hip_bf16.h>

#define T_SEQ 2048
#define CDIM 512
#define HDIM 8
#define DHEAD 64
#define BT 4096   // B*T

// ---------------------------------------------------------------------------
// Kernel 1: elementwise tanh of x and the three weight matrices
// ---------------------------------------------------------------------------
__global__ __launch_bounds__(256) void tanh_prep(
    const float* __restrict__ x,  const float* __restrict__ wq,
    const float* __restrict__ wk, const float* __restrict__ wv,
    float* __restrict__ xact, float* __restrict__ wqa,
    float* __restrict__ wka,  float* __restrict__ wva)
{
    const int NX = BT * CDIM / 4;     // 524288 float4
    const int NW = CDIM * CDIM / 4;   // 65536 float4
    int idx = blockIdx.x * 256 + threadIdx.x;
    const float4* src; float4* dst; int off;
    if (idx < NX)           { src = (const float4*)x;  dst = (float4*)xact; off = idx; }
    else if (idx < NX+NW)   { src = (const float4*)wq; dst = (float4*)wqa;  off = idx - NX; }
    else if (idx < NX+2*NW) { src = (const float4*)wk; dst = (float4*)wka;  off = idx - NX - NW; }
    else                    { src = (const float4*)wv; dst = (float4*)wva;  off = idx - NX - 2*NW; }
    float4 t = src[off];
    t.x = tanhf(t.x); t.y = tanhf(t.y); t.z = tanhf(t.z); t.w = tanhf(t.w);
    dst[off] = t;
}

// ---------------------------------------------------------------------------
// Kernel 2: L1-cdist projection. 64x128 tile, 256 threads, 4x8 micro-tile.
// a-rows = ty+16i (i<4), b-rows = tx+16j (j<8). Grid (4, 64, 3) = 768 = 3/CU.
// ---------------------------------------------------------------------------
#define PSTR 36
__global__ __launch_bounds__(256) void proj_l1(
    const float* __restrict__ xact,
    const float* __restrict__ wqa, const float* __restrict__ wka, const float* __restrict__ wva,
    const float* __restrict__ gq,  const float* __restrict__ gk,  const float* __restrict__ gv,
    float* __restrict__ oq, float* __restrict__ okk, float* __restrict__ ov)
{
    __shared__ float As[64][PSTR];
    __shared__ float Bs[128][PSTR];

    const int z = blockIdx.z;
    const float* w    = (z == 0) ? wqa : (z == 1) ? wka : wva;
    const float* gain = (z == 0) ? gq  : (z == 1) ? gk  : gv;
    float* outp       = (z == 0) ? oq  : (z == 1) ? okk : ov;

    const int row0 = blockIdx.y * 64;
    const int col0 = blockIdx.x * 128;
    const int tid = threadIdx.x;
    const int tx = tid & 15, ty = tid >> 4;

    float acc[4][8];
    #pragma unroll
    for (int i = 0; i < 4; ++i)
        #pragma unroll
        for (int j = 0; j < 8; ++j) acc[i][j] = 0.f;

    for (int k0 = 0; k0 < CDIM; k0 += 32) {
        // stage A (64x32 = 512 f4, 2/thread) and B (128x32 = 1024 f4, 4/thread)
        float4 av[2], bv[4];
        #pragma unroll
        for (int q = 0; q < 2; ++q) {
            const int fi = tid + 256 * q;
            av[q] = *(const float4*)&xact[(size_t)(row0 + (fi >> 3)) * CDIM + k0 + 4*(fi & 7)];
        }
        #pragma unroll
        for (int q = 0; q < 4; ++q) {
            const int fi = tid + 256 * q;
            bv[q] = *(const float4*)&w[(size_t)(col0 + (fi >> 3)) * CDIM + k0 + 4*(fi & 7)];
        }
        __syncthreads();
        #pragma unroll
        for (int q = 0; q < 2; ++q) {
            const int fi = tid + 256 * q;
            *(float4*)&As[fi >> 3][4*(fi & 7)] = av[q];
        }
        #pragma unroll
        for (int q = 0; q < 4; ++q) {
            const int fi = tid + 256 * q;
            *(float4*)&Bs[fi >> 3][4*(fi & 7)] = bv[q];
        }
        __syncthreads();

        #pragma unroll 2
        for (int kk = 0; kk < 32; kk += 4) {
            float4 a4[4], b4[8];
            #pragma unroll
            for (int i = 0; i < 4; ++i) a4[i] = *(const float4*)&As[ty + 16*i][kk];
            #pragma unroll
            for (int j = 0; j < 8; ++j) b4[j] = *(const float4*)&Bs[tx + 16*j][kk];
            #pragma unroll
            for (int i = 0; i < 4; ++i)
                #pragma unroll
                for (int j = 0; j < 8; ++j)
                    acc[i][j] += fabsf(a4[i].x - b4[j].x) + fabsf(a4[i].y - b4[j].y)
                               + fabsf(a4[i].z - b4[j].z) + fabsf(a4[i].w - b4[j].w);
        }
        __syncthreads();
    }

    float gcol[8];
    #pragma unroll
    for (int j = 0; j < 8; ++j) gcol[j] = gain[col0 + tx + 16*j];

    #pragma unroll
    for (int i = 0; i < 4; ++i) {
        const int r = row0 + ty + 16*i;
        #pragma unroll
        for (int j = 0; j < 8; ++j) {
            const int c = col0 + tx + 16*j;
            float val = (0.5f - acc[i][j] * (1.0f / 512.0f)) * gcol[j];
            if (z < 2) val = tanhf(val);
            outp[(size_t)r * CDIM + c] = val;
        }
    }
}

// ---------------------------------------------------------------------------
// Kernel 3: causal L1-kernel attention. Strip = 128 q-rows (Q in LDS once),
// k-tile = 128, 8x8 score micro-tile, PV via quarter-K W buffer.
// Chunks of <=4 k-tiles -> 4 atomic-free slabs. Grid (16 bh, 40 slots).
// LDS strides: 68 for 64-wide data tiles (4 mod 32 -> 2-way, 16B aligned),
// 36 for the 32-wide W quarters.
// ---------------------------------------------------------------------------
__global__ __launch_bounds__(256) void attn_l1(
    const float* __restrict__ qg, const float* __restrict__ kg, const float* __restrict__ vg,
    const float* __restrict__ gamma, const float* __restrict__ rho,
    float* __restrict__ slabv, float* __restrict__ slabs)
{
    __shared__ float Qs[128][68];
    __shared__ float Ks[128][68];
    __shared__ float Vs[128][68];
    __shared__ float Ws[128][36];

    const int bh = blockIdx.x;
    const int b = bh >> 3, h = bh & 7;

    // decode slot -> (strip s, chunk c); big strips first
    int slot = blockIdx.y;
    int s = 15, c = 0;
    for (;; --s) {
        const int nc = (s >> 2) + 1;
        if (slot < nc) { c = slot; break; }
        slot -= nc;
    }
    const int i0 = s * 128;
    const int kt0 = 4 * c;
    const int kt1 = min(4 * c + 3, s);

    const int tid = threadIdx.x;
    const int tx = tid & 15, ty = tid >> 4;
    const int gr = tid >> 3;          // 0..31 loader row
    const int gc = (tid & 7) * 4;     // 0..28 loader col

    const float gp = log1pf(__expf(gamma[h]));
    const float rp = log1pf(__expf(rho[h]));
    const float gp64 = gp * (1.0f / 64.0f);   // gp * 0.125^2
    const float mrho = -rp;

    const size_t hb = (size_t)b * T_SEQ * CDIM + h * DHEAD;

    // ---- load Q strip (128 x 64) into LDS ----
    #pragma unroll
    for (int p = 0; p < 4; ++p)
        #pragma unroll
        for (int h2 = 0; h2 < 2; ++h2)
            *(float4*)&Qs[gr + 32*p][gc + 32*h2] =
                *(const float4*)&qg[hb + (size_t)(i0 + gr + 32*p) * CDIM + gc + 32*h2];

    float4 o4[8];
    float accs[8];
    float l1w[8][8];
    #pragma unroll
    for (int i = 0; i < 8; ++i) {
        o4[i] = make_float4(0.f, 0.f, 0.f, 0.f);
        accs[i] = 0.f;
    }

    for (int kt = kt0; kt <= kt1; ++kt) {
        const int j0 = kt * 128;
        __syncthreads();   // prev tile's PV reads + Q writes done
        #pragma unroll
        for (int p = 0; p < 4; ++p)
            #pragma unroll
            for (int h2 = 0; h2 < 2; ++h2) {
                const size_t off = hb + (size_t)(j0 + gr + 32*p) * CDIM + gc + 32*h2;
                *(float4*)&Ks[gr + 32*p][gc + 32*h2] = *(const float4*)&kg[off];
                *(float4*)&Vs[gr + 32*p][gc + 32*h2] = *(const float4*)&vg[off];
            }
        __syncthreads();

        // ---- scores: L1 over d=64; q-rows ty+16i, k-rows tx+16j ----
        #pragma unroll
        for (int i = 0; i < 8; ++i)
            #pragma unroll
            for (int j = 0; j < 8; ++j) l1w[i][j] = 0.f;

        #pragma unroll 2
        for (int d0 = 0; d0 < DHEAD; d0 += 4) {
            float4 a4[8];
            #pragma unroll
            for (int i = 0; i < 8; ++i) a4[i] = *(const float4*)&Qs[ty + 16*i][d0];
            #pragma unroll
            for (int j = 0; j < 8; ++j) {
                const float4 kx = *(const float4*)&Ks[tx + 16*j][d0];
                #pragma unroll
                for (int i = 0; i < 8; ++i)
                    l1w[i][j] += fabsf(a4[i].x - kx.x) + fabsf(a4[i].y - kx.y)
                               + fabsf(a4[i].z - kx.z) + fabsf(a4[i].w - kx.w);
            }
        }

        // ---- kernel function + causal mask (diag tile only) ----
        const bool diag = (kt == s);
        #pragma unroll
        for (int i = 0; i < 8; ++i)
            #pragma unroll
            for (int j = 0; j < 8; ++j) {
                const float l1 = l1w[i][j];
                const float den = fmaf(gp64 * l1, l1, 1.000001f);
                float wgt = __builtin_amdgcn_exp2f(mrho * __builtin_amdgcn_logf(den));
                if (diag && (tx + 16*j) > (ty + 16*i)) wgt = 0.f;
                l1w[i][j] = wgt;
                accs[i] += wgt;
            }

        // ---- PV in four 32-k quarters through Ws ----
        #pragma unroll
        for (int qtr = 0; qtr < 4; ++qtr) {
            __syncthreads();   // prev quarter's Ws reads done
            #pragma unroll
            for (int i = 0; i < 8; ++i) {
                Ws[ty + 16*i][tx]      = l1w[i][2*qtr];
                Ws[ty + 16*i][tx + 16] = l1w[i][2*qtr + 1];
            }
            __syncthreads();

            #pragma unroll 2
            for (int jc = 0; jc < 32; jc += 4) {
                float4 w4[8], v4[4];
                #pragma unroll
                for (int i = 0; i < 8; ++i) w4[i] = *(const float4*)&Ws[ty + 16*i][jc];
                #pragma unroll
                for (int jj = 0; jj < 4; ++jj)
                    v4[jj] = *(const float4*)&Vs[qtr*32 + jc + jj][tx*4];
                #pragma unroll
                for (int i = 0; i < 8; ++i) {
                    o4[i].x += w4[i].x*v4[0].x + w4[i].y*v4[1].x + w4[i].z*v4[2].x + w4[i].w*v4[3].x;
                    o4[i].y += w4[i].x*v4[0].y + w4[i].y*v4[1].y + w4[i].z*v4[2].y + w4[i].w*v4[3].y;
                    o4[i].z += w4[i].x*v4[0].z + w4[i].y*v4[1].z + w4[i].z*v4[2].z + w4[i].w*v4[3].z;
                    o4[i].w += w4[i].x*v4[0].w + w4[i].y*v4[1].w + w4[i].z*v4[2].w + w4[i].w*v4[3].w;
                }
            }
        }
    }

    // ---- row-sum reduction over the 16 tx lanes (in-wave) ----
    #pragma unroll
    for (int i = 0; i < 8; ++i) {
        accs[i] += __shfl_xor(accs[i], 1, 64);
        accs[i] += __shfl_xor(accs[i], 2, 64);
        accs[i] += __shfl_xor(accs[i], 4, 64);
        accs[i] += __shfl_xor(accs[i], 8, 64);
    }

    // ---- store partials into this chunk's slab ----
    float* sv = slabv + (size_t)c * ((size_t)BT * CDIM);
    float* ss = slabs + (size_t)c * ((size_t)BT * HDIM);
    #pragma unroll
    for (int i = 0; i < 8; ++i) {
        const int qr = i0 + ty + 16*i;
        if (tx == 0)
            ss[(size_t)(b * T_SEQ + qr) * HDIM + h] = accs[i];
        *(float4*)&sv[hb + (size_t)qr * CDIM + tx*4] = o4[i];
    }
}

// ---------------------------------------------------------------------------
// Kernel 4: normalize: ab = (sum_c slabv[c]) / (sum_c slabs[c] + 1e-6),
// summing only chunks that exist for this row's strip (nch = s/4 + 1).
// ---------------------------------------------------------------------------
__global__ __launch_bounds__(256) void normalize_k(
    const float* __restrict__ slabv, const float* __restrict__ slabs,
    float* __restrict__ ab)
{
    int idx = blockIdx.x * 256 + threadIdx.x;   // < 524288 float4
    const int row = idx >> 7;          // 128 float4 per row of 512
    const int col = (idx & 127) << 2;
    const int h = col >> 6;
    const int t = row & (T_SEQ - 1);
    const int nch = ((t >> 7) >> 2) + 1;         // strip s = t/128; s/4 + 1

    const size_t NV = (size_t)BT * CDIM / 4;
    const size_t NS = (size_t)BT * HDIM;
    float4 v = ((const float4*)slabv)[idx];
    float ssum = slabs[(size_t)row * HDIM + h];
    #pragma unroll
    for (int c = 1; c < 4; ++c) {
        if (c < nch) {
            float4 u = ((const float4*)slabv)[c * NV + idx];
            v.x += u.x; v.y += u.y; v.z += u.z; v.w += u.w;
            ssum += slabs[c * NS + (size_t)row * HDIM + h];
        }
    }
    const float inv = 1.0f / (ssum + 1e-6f);
    v.x *= inv; v.y *= inv; v.z *= inv; v.w *= inv;
    ((float4*)ab)[idx] = v;
}

// ---------------------------------------------------------------------------
// Kernel 5: output projection Y = A @ wo^T + bias. M=4096, N=512, K=512.
// 128x64 tile, 8x4 micro. Grid (8, 32) = 256 blocks = 1/CU.
// ---------------------------------------------------------------------------
__global__ __launch_bounds__(256) void out_gemm(
    const float* __restrict__ A, const float* __restrict__ wo,
    const float* __restrict__ bias, float* __restrict__ Y)
{
    __shared__ float As[128][PSTR];
    __shared__ float Bs[64][PSTR];

    const int row0 = blockIdx.y * 128;
    const int col0 = blockIdx.x * 64;
    const int tid = threadIdx.x;
    const int tx = tid & 15, ty = tid >> 4;
    const int lr = tid >> 3;
    const int lc = (tid & 7) * 4;

    float acc[8][4];
    #pragma unroll
    for (int i = 0; i < 8; ++i)
        #pragma unroll
        for (int j = 0; j < 4; ++j) acc[i][j] = 0.f;

    for (int k0 = 0; k0 < CDIM; k0 += 32) {
        float4 ar[4];
        #pragma unroll
        for (int p = 0; p < 4; ++p)
            ar[p] = *(const float4*)&A[(size_t)(row0 + lr + 32*p) * CDIM + k0 + lc];
        float4 b0 = *(const float4*)&wo[(size_t)(col0 + lr)      * CDIM + k0 + lc];
        float4 b1 = *(const float4*)&wo[(size_t)(col0 + lr + 32) * CDIM + k0 + lc];
        __syncthreads();
        #pragma unroll
        for (int p = 0; p < 4; ++p)
            *(float4*)&As[lr + 32*p][lc] = ar[p];
        *(float4*)&Bs[lr][lc]      = b0;
        *(float4*)&Bs[lr + 32][lc] = b1;
        __syncthreads();

        #pragma unroll
        for (int kk = 0; kk < 32; kk += 4) {
            float4 a4[8], b4[4];
            #pragma unroll
            for (int i = 0; i < 8; ++i) a4[i] = *(const float4*)&As[ty + 16*i][kk];
            #pragma unroll
            for (int j = 0; j < 4; ++j) b4[j] = *(const float4*)&Bs[tx + 16*j][kk];
            #pragma unroll
            for (int i = 0; i < 8; ++i)
                #pragma unroll
                for (int j = 0; j < 4; ++j)
                    acc[i][j] += a4[i].x * b4[j].x + a4[i].y * b4[j].y
                               + a4[i].z * b4[j].z + a4[i].w * b4[j].w;
        }
    }

    float bcol[4];
    #pragma unroll
    for (int j = 0; j < 4; ++j) bcol[j] = bias[col0 + tx + 16*j];

    #pragma unroll
    for (int i = 0; i < 8; ++i) {
        const int r = row0 + ty + 16*i;
        #pragma unroll
        for (int j = 0; j < 4; ++j) {
            const int c = col0 + tx + 16*j;
            Y[(size_t)r * CDIM + c] = acc[i][j] + bcol[j];
        }
    }
}

// ---------------------------------------------------------------------------
extern "C" void kernel_launch(void* const* d_in, const int* in_sizes, int n_in,
                              void* d_out, int out_size, void* d_ws, size_t ws_size,
                              hipStream_t stream)
{
    (void)in_sizes; (void)n_in; (void)out_size; (void)ws_size;
    const float* x     = (const float*)d_in[0];
    // d_in[1] = mask (causal tril; semantics hardcoded)
    const float* wq    = (const float*)d_in[2];
    const float* gq    = (const float*)d_in[3];
    const float* wk    = (const float*)d_in[4];
    const float* gk    = (const float*)d_in[5];
    const float* wv    = (const float*)d_in[6];
    const float* gv    = (const float*)d_in[7];
    const float* wo    = (const float*)d_in[8];
    const float* wob   = (const float*)d_in[9];
    const float* gamma = (const float*)d_in[10];
    const float* rho   = (const float*)d_in[11];
    float* out = (float*)d_out;

    const size_t NV = (size_t)BT * CDIM;   // 2,097,152 floats
    const size_t NW = (size_t)CDIM * CDIM; //   262,144
    const size_t NS = (size_t)BT * HDIM;   //    32,768

    float* ws    = (float*)d_ws;
    float* xact  = ws;                 // NV
    float* wqa   = xact + NV;          // NW
    float* wka   = wqa + NW;
    float* wva   = wka + NW;
    float* qb    = wva + NW;           // NV
    float* kb    = qb + NV;
    float* vb    = kb + NV;
    float* slabv = vb + NV;            // 4*NV
    float* slabs = slabv + 4 * NV;     // 4*NS
    float* ab    = qb;                 // alias: qb dead after attn_l1

    tanh_prep<<<2816, 256, 0, stream>>>(x, wq, wk, wv, xact, wqa, wka, wva);
    proj_l1<<<dim3(4, 64, 3), 256, 0, stream>>>(xact, wqa, wka, wva,
                                                gq, gk, gv, qb, kb, vb);
    attn_l1<<<dim3(16, 40), 256, 0, stream>>>(qb, kb, vb, gamma, rho, slabv, slabs);
    normalize_k<<<2048, 256, 0, stream>>>(slabv, slabs, ab);
    out_gemm<<<dim3(8, 32), 256, 0, stream>>>(ab, wo, wob, out);
}

// Round 7
// 637.701 us; speedup vs baseline: 1.8913x; 1.0574x over previous
//
#include <hip/hip_runtime.h>
#include <hip/hip_bf16.h>

#define T_SEQ 2048
#define CDIM 512
#define HDIM 8
#define DHEAD 64
#define BT 4096   // B*T

// ---------------------------------------------------------------------------
// Kernel 1: elementwise tanh of x and the three weight matrices
// ---------------------------------------------------------------------------
__global__ __launch_bounds__(256) void tanh_prep(
    const float* __restrict__ x,  const float* __restrict__ wq,
    const float* __restrict__ wk, const float* __restrict__ wv,
    float* __restrict__ xact, float* __restrict__ wqa,
    float* __restrict__ wka,  float* __restrict__ wva)
{
    const int NX = BT * CDIM / 4;     // 524288 float4
    const int NW = CDIM * CDIM / 4;   // 65536 float4
    int idx = blockIdx.x * 256 + threadIdx.x;
    const float4* src; float4* dst; int off;
    if (idx < NX)           { src = (const float4*)x;  dst = (float4*)xact; off = idx; }
    else if (idx < NX+NW)   { src = (const float4*)wq; dst = (float4*)wqa;  off = idx - NX; }
    else if (idx < NX+2*NW) { src = (const float4*)wk; dst = (float4*)wka;  off = idx - NX - NW; }
    else                    { src = (const float4*)wv; dst = (float4*)wva;  off = idx - NX - 2*NW; }
    float4 t = src[off];
    t.x = tanhf(t.x); t.y = tanhf(t.y); t.z = tanhf(t.z); t.w = tanhf(t.w);
    dst[off] = t;
}

// ---------------------------------------------------------------------------
// Kernel 2: L1-cdist projection. 64x128 tile, 256 threads, 4x8 micro-tile.
// ---------------------------------------------------------------------------
#define PSTR 36
__global__ __launch_bounds__(256) void proj_l1(
    const float* __restrict__ xact,
    const float* __restrict__ wqa, const float* __restrict__ wka, const float* __restrict__ wva,
    const float* __restrict__ gq,  const float* __restrict__ gk,  const float* __restrict__ gv,
    float* __restrict__ oq, float* __restrict__ okk, float* __restrict__ ov)
{
    __shared__ float As[64][PSTR];
    __shared__ float Bs[128][PSTR];

    const int z = blockIdx.z;
    const float* w    = (z == 0) ? wqa : (z == 1) ? wka : wva;
    const float* gain = (z == 0) ? gq  : (z == 1) ? gk  : gv;
    float* outp       = (z == 0) ? oq  : (z == 1) ? okk : ov;

    const int row0 = blockIdx.y * 64;
    const int col0 = blockIdx.x * 128;
    const int tid = threadIdx.x;
    const int tx = tid & 15, ty = tid >> 4;

    float acc[4][8];
    #pragma unroll
    for (int i = 0; i < 4; ++i)
        #pragma unroll
        for (int j = 0; j < 8; ++j) acc[i][j] = 0.f;

    for (int k0 = 0; k0 < CDIM; k0 += 32) {
        float4 av[2], bv[4];
        #pragma unroll
        for (int q = 0; q < 2; ++q) {
            const int fi = tid + 256 * q;
            av[q] = *(const float4*)&xact[(size_t)(row0 + (fi >> 3)) * CDIM + k0 + 4*(fi & 7)];
        }
        #pragma unroll
        for (int q = 0; q < 4; ++q) {
            const int fi = tid + 256 * q;
            bv[q] = *(const float4*)&w[(size_t)(col0 + (fi >> 3)) * CDIM + k0 + 4*(fi & 7)];
        }
        __syncthreads();
        #pragma unroll
        for (int q = 0; q < 2; ++q) {
            const int fi = tid + 256 * q;
            *(float4*)&As[fi >> 3][4*(fi & 7)] = av[q];
        }
        #pragma unroll
        for (int q = 0; q < 4; ++q) {
            const int fi = tid + 256 * q;
            *(float4*)&Bs[fi >> 3][4*(fi & 7)] = bv[q];
        }
        __syncthreads();

        #pragma unroll 2
        for (int kk = 0; kk < 32; kk += 4) {
            float4 a4[4], b4[8];
            #pragma unroll
            for (int i = 0; i < 4; ++i) a4[i] = *(const float4*)&As[ty + 16*i][kk];
            #pragma unroll
            for (int j = 0; j < 8; ++j) b4[j] = *(const float4*)&Bs[tx + 16*j][kk];
            #pragma unroll
            for (int i = 0; i < 4; ++i)
                #pragma unroll
                for (int j = 0; j < 8; ++j)
                    acc[i][j] += fabsf(a4[i].x - b4[j].x) + fabsf(a4[i].y - b4[j].y)
                               + fabsf(a4[i].z - b4[j].z) + fabsf(a4[i].w - b4[j].w);
        }
        __syncthreads();
    }

    float gcol[8];
    #pragma unroll
    for (int j = 0; j < 8; ++j) gcol[j] = gain[col0 + tx + 16*j];

    #pragma unroll
    for (int i = 0; i < 4; ++i) {
        const int r = row0 + ty + 16*i;
        #pragma unroll
        for (int j = 0; j < 8; ++j) {
            const int c = col0 + tx + 16*j;
            float val = (0.5f - acc[i][j] * (1.0f / 512.0f)) * gcol[j];
            if (z < 2) val = tanhf(val);
            outp[(size_t)r * CDIM + c] = val;
        }
    }
}

// ---------------------------------------------------------------------------
// Kernel 3: causal L1-kernel attention.
// Strip = 128 q-rows (Qs in LDS once). k-tile = 64 with W aliased onto Ks
// (K dead after scores) -> LDS 69 KB -> 2 blocks/CU (2 waves/SIMD).
// Next-tile K/V prefetched into registers (T14). 8x4 score micro-tile,
// PV in two 32-k halves through the KW union. Chunks of <=8 k-tiles ->
// 4 atomic-free slabs (same 512-col chunks as before). Grid (16 bh, 40).
// ---------------------------------------------------------------------------
__global__ __launch_bounds__(256, 2) void attn_l1(
    const float* __restrict__ qg, const float* __restrict__ kg, const float* __restrict__ vg,
    const float* __restrict__ gamma, const float* __restrict__ rho,
    float* __restrict__ slabv, float* __restrict__ slabs)
{
    __shared__ float Qs[128][68];
    __shared__ float Vs[64][68];
    __shared__ float KW[4608];   // union: Ks[64][68] (4352 f) / Ws[128][36] (4608 f)

    const int bh = blockIdx.x;
    const int b = bh >> 3, h = bh & 7;

    // decode slot -> (strip s, chunk c); big strips first
    int slot = blockIdx.y;
    int s = 15, c = 0;
    for (;; --s) {
        const int nc = (s >> 2) + 1;
        if (slot < nc) { c = slot; break; }
        slot -= nc;
    }
    const int i0 = s * 128;
    const int kt0 = 8 * c;
    const int kt1 = min(8 * c + 7, 2 * s + 1);

    const int tid = threadIdx.x;
    const int tx = tid & 15, ty = tid >> 4;

    const float gp = log1pf(__expf(gamma[h]));
    const float rp = log1pf(__expf(rho[h]));
    const float gp64 = gp * (1.0f / 64.0f);   // gp * 0.125^2
    const float mrho = -rp;

    const size_t hb = (size_t)b * T_SEQ * CDIM + h * DHEAD;

    // ---- load Q strip (128 x 64) into LDS ----
    {
        const int gr = tid >> 3;          // 0..31
        const int gc = (tid & 7) * 4;     // 0..28
        #pragma unroll
        for (int p = 0; p < 4; ++p)
            #pragma unroll
            for (int h2 = 0; h2 < 2; ++h2)
                *(float4*)&Qs[gr + 32*p][gc + 32*h2] =
                    *(const float4*)&qg[hb + (size_t)(i0 + gr + 32*p) * CDIM + gc + 32*h2];
    }

    // ---- prefetch first K/V tile (64 x 64 each; 4 float4 per thread each) ----
    float4 kpre[4], vpre[4];
    {
        const int j0 = kt0 * 64;
        #pragma unroll
        for (int q = 0; q < 4; ++q) {
            const int fi = tid + 256 * q;                 // 0..1023
            const size_t off = hb + (size_t)(j0 + (fi >> 4)) * CDIM + 4 * (fi & 15);
            kpre[q] = *(const float4*)&kg[off];
            vpre[q] = *(const float4*)&vg[off];
        }
    }

    float4 o4[8];
    float accs[8];
    float l1w[8][4];
    #pragma unroll
    for (int i = 0; i < 8; ++i) {
        o4[i] = make_float4(0.f, 0.f, 0.f, 0.f);
        accs[i] = 0.f;
    }

    for (int kt = kt0; kt <= kt1; ++kt) {
        __syncthreads();   // prev tile's PV2 done reading KW/Vs; Qs writes done
        {   // write staged K/V, then issue next tile's loads
            #pragma unroll
            for (int q = 0; q < 4; ++q) {
                const int fi = tid + 256 * q;
                const int r = fi >> 4, c4 = 4 * (fi & 15);
                *(float4*)&KW[r * 68 + c4] = kpre[q];
                *(float4*)&Vs[r][c4]       = vpre[q];
            }
            const int nkt = (kt + 1 <= kt1) ? kt + 1 : kt1;
            const int nj0 = nkt * 64;
            #pragma unroll
            for (int q = 0; q < 4; ++q) {
                const int fi = tid + 256 * q;
                const size_t off = hb + (size_t)(nj0 + (fi >> 4)) * CDIM + 4 * (fi & 15);
                kpre[q] = *(const float4*)&kg[off];
                vpre[q] = *(const float4*)&vg[off];
            }
        }
        __syncthreads();

        // ---- scores: L1 over d=64; q-rows ty+16i (i<8), k-rows tx+16j (j<4) ----
        #pragma unroll
        for (int i = 0; i < 8; ++i)
            #pragma unroll
            for (int j = 0; j < 4; ++j) l1w[i][j] = 0.f;

        #pragma unroll 2
        for (int d0 = 0; d0 < DHEAD; d0 += 4) {
            float4 a4[8];
            #pragma unroll
            for (int i = 0; i < 8; ++i) a4[i] = *(const float4*)&Qs[ty + 16*i][d0];
            #pragma unroll
            for (int j = 0; j < 4; ++j) {
                const float4 kx = *(const float4*)&KW[(tx + 16*j) * 68 + d0];
                #pragma unroll
                for (int i = 0; i < 8; ++i)
                    l1w[i][j] += fabsf(a4[i].x - kx.x) + fabsf(a4[i].y - kx.y)
                               + fabsf(a4[i].z - kx.z) + fabsf(a4[i].w - kx.w);
            }
        }

        // ---- kernel function + causal mask (diagonal tiles only) ----
        const int j0 = kt * 64;
        const bool diag = (kt >= 2 * s);
        #pragma unroll
        for (int i = 0; i < 8; ++i)
            #pragma unroll
            for (int j = 0; j < 4; ++j) {
                const float l1 = l1w[i][j];
                const float den = fmaf(gp64 * l1, l1, 1.000001f);
                float wgt = __builtin_amdgcn_exp2f(mrho * __builtin_amdgcn_logf(den));
                if (diag && (j0 + tx + 16*j) > (i0 + ty + 16*i)) wgt = 0.f;
                l1w[i][j] = wgt;
                accs[i] += wgt;
            }

        // ---- PV in two 32-k halves through the KW union (K now dead) ----
        #pragma unroll
        for (int hh = 0; hh < 2; ++hh) {
            __syncthreads();   // hh=0: K reads done; hh=1: PV1's W reads done
            #pragma unroll
            for (int i = 0; i < 8; ++i) {
                KW[(ty + 16*i) * 36 + tx]      = l1w[i][2*hh];
                KW[(ty + 16*i) * 36 + tx + 16] = l1w[i][2*hh + 1];
            }
            __syncthreads();

            #pragma unroll 2
            for (int jc = 0; jc < 32; jc += 4) {
                float4 w4[8], v4[4];
                #pragma unroll
                for (int i = 0; i < 8; ++i)
                    w4[i] = *(const float4*)&KW[(ty + 16*i) * 36 + jc];
                #pragma unroll
                for (int jj = 0; jj < 4; ++jj)
                    v4[jj] = *(const float4*)&Vs[32*hh + jc + jj][tx*4];
                #pragma unroll
                for (int i = 0; i < 8; ++i) {
                    o4[i].x += w4[i].x*v4[0].x + w4[i].y*v4[1].x + w4[i].z*v4[2].x + w4[i].w*v4[3].x;
                    o4[i].y += w4[i].x*v4[0].y + w4[i].y*v4[1].y + w4[i].z*v4[2].y + w4[i].w*v4[3].y;
                    o4[i].z += w4[i].x*v4[0].z + w4[i].y*v4[1].z + w4[i].z*v4[2].z + w4[i].w*v4[3].z;
                    o4[i].w += w4[i].x*v4[0].w + w4[i].y*v4[1].w + w4[i].z*v4[2].w + w4[i].w*v4[3].w;
                }
            }
        }
    }

    // ---- row-sum reduction over the 16 tx lanes (in-wave) ----
    #pragma unroll
    for (int i = 0; i < 8; ++i) {
        accs[i] += __shfl_xor(accs[i], 1, 64);
        accs[i] += __shfl_xor(accs[i], 2, 64);
        accs[i] += __shfl_xor(accs[i], 4, 64);
        accs[i] += __shfl_xor(accs[i], 8, 64);
    }

    // ---- store partials into this chunk's slab ----
    float* sv = slabv + (size_t)c * ((size_t)BT * CDIM);
    float* ss = slabs + (size_t)c * ((size_t)BT * HDIM);
    #pragma unroll
    for (int i = 0; i < 8; ++i) {
        const int qr = i0 + ty + 16*i;
        if (tx == 0)
            ss[(size_t)(b * T_SEQ + qr) * HDIM + h] = accs[i];
        *(float4*)&sv[hb + (size_t)qr * CDIM + tx*4] = o4[i];
    }
}

// ---------------------------------------------------------------------------
// Kernel 4: normalize: ab = (sum_c slabv[c]) / (sum_c slabs[c] + 1e-6),
// summing only chunks that exist for this row's strip (nch = s/4 + 1).
// ---------------------------------------------------------------------------
__global__ __launch_bounds__(256) void normalize_k(
    const float* __restrict__ slabv, const float* __restrict__ slabs,
    float* __restrict__ ab)
{
    int idx = blockIdx.x * 256 + threadIdx.x;   // < 524288 float4
    const int row = idx >> 7;          // 128 float4 per row of 512
    const int col = (idx & 127) << 2;
    const int h = col >> 6;
    const int t = row & (T_SEQ - 1);
    const int nch = ((t >> 7) >> 2) + 1;         // strip s = t/128; s/4 + 1

    const size_t NV = (size_t)BT * CDIM / 4;
    const size_t NS = (size_t)BT * HDIM;
    float4 v = ((const float4*)slabv)[idx];
    float ssum = slabs[(size_t)row * HDIM + h];
    #pragma unroll
    for (int c = 1; c < 4; ++c) {
        if (c < nch) {
            float4 u = ((const float4*)slabv)[c * NV + idx];
            v.x += u.x; v.y += u.y; v.z += u.z; v.w += u.w;
            ssum += slabs[c * NS + (size_t)row * HDIM + h];
        }
    }
    const float inv = 1.0f / (ssum + 1e-6f);
    v.x *= inv; v.y *= inv; v.z *= inv; v.w *= inv;
    ((float4*)ab)[idx] = v;
}

// ---------------------------------------------------------------------------
// Kernel 5: output projection Y = A @ wo^T + bias. M=4096, N=512, K=512.
// 128x64 tile, 8x4 micro. Grid (8, 32) = 256 blocks.
// ---------------------------------------------------------------------------
__global__ __launch_bounds__(256) void out_gemm(
    const float* __restrict__ A, const float* __restrict__ wo,
    const float* __restrict__ bias, float* __restrict__ Y)
{
    __shared__ float As[128][PSTR];
    __shared__ float Bs[64][PSTR];

    const int row0 = blockIdx.y * 128;
    const int col0 = blockIdx.x * 64;
    const int tid = threadIdx.x;
    const int tx = tid & 15, ty = tid >> 4;
    const int lr = tid >> 3;
    const int lc = (tid & 7) * 4;

    float acc[8][4];
    #pragma unroll
    for (int i = 0; i < 8; ++i)
        #pragma unroll
        for (int j = 0; j < 4; ++j) acc[i][j] = 0.f;

    for (int k0 = 0; k0 < CDIM; k0 += 32) {
        float4 ar[4];
        #pragma unroll
        for (int p = 0; p < 4; ++p)
            ar[p] = *(const float4*)&A[(size_t)(row0 + lr + 32*p) * CDIM + k0 + lc];
        float4 b0 = *(const float4*)&wo[(size_t)(col0 + lr)      * CDIM + k0 + lc];
        float4 b1 = *(const float4*)&wo[(size_t)(col0 + lr + 32) * CDIM + k0 + lc];
        __syncthreads();
        #pragma unroll
        for (int p = 0; p < 4; ++p)
            *(float4*)&As[lr + 32*p][lc] = ar[p];
        *(float4*)&Bs[lr][lc]      = b0;
        *(float4*)&Bs[lr + 32][lc] = b1;
        __syncthreads();

        #pragma unroll
        for (int kk = 0; kk < 32; kk += 4) {
            float4 a4[8], b4[4];
            #pragma unroll
            for (int i = 0; i < 8; ++i) a4[i] = *(const float4*)&As[ty + 16*i][kk];
            #pragma unroll
            for (int j = 0; j < 4; ++j) b4[j] = *(const float4*)&Bs[tx + 16*j][kk];
            #pragma unroll
            for (int i = 0; i < 8; ++i)
                #pragma unroll
                for (int j = 0; j < 4; ++j)
                    acc[i][j] += a4[i].x * b4[j].x + a4[i].y * b4[j].y
                               + a4[i].z * b4[j].z + a4[i].w * b4[j].w;
        }
    }

    float bcol[4];
    #pragma unroll
    for (int j = 0; j < 4; ++j) bcol[j] = bias[col0 + tx + 16*j];

    #pragma unroll
    for (int i = 0; i < 8; ++i) {
        const int r = row0 + ty + 16*i;
        #pragma unroll
        for (int j = 0; j < 4; ++j) {
            const int c = col0 + tx + 16*j;
            Y[(size_t)r * CDIM + c] = acc[i][j] + bcol[j];
        }
    }
}

// ---------------------------------------------------------------------------
extern "C" void kernel_launch(void* const* d_in, const int* in_sizes, int n_in,
                              void* d_out, int out_size, void* d_ws, size_t ws_size,
                              hipStream_t stream)
{
    (void)in_sizes; (void)n_in; (void)out_size; (void)ws_size;
    const float* x     = (const float*)d_in[0];
    // d_in[1] = mask (causal tril; semantics hardcoded)
    const float* wq    = (const float*)d_in[2];
    const float* gq    = (const float*)d_in[3];
    const float* wk    = (const float*)d_in[4];
    const float* gk    = (const float*)d_in[5];
    const float* wv    = (const float*)d_in[6];
    const float* gv    = (const float*)d_in[7];
    const float* wo    = (const float*)d_in[8];
    const float* wob   = (const float*)d_in[9];
    const float* gamma = (const float*)d_in[10];
    const float* rho   = (const float*)d_in[11];
    float* out = (float*)d_out;

    const size_t NV = (size_t)BT * CDIM;   // 2,097,152 floats
    const size_t NW = (size_t)CDIM * CDIM; //   262,144
    const size_t NS = (size_t)BT * HDIM;   //    32,768

    float* ws    = (float*)d_ws;
    float* xact  = ws;                 // NV
    float* wqa   = xact + NV;          // NW
    float* wka   = wqa + NW;
    float* wva   = wka + NW;
    float* qb    = wva + NW;           // NV
    float* kb    = qb + NV;
    float* vb    = kb + NV;
    float* slabv = vb + NV;            // 4*NV
    float* slabs = slabv + 4 * NV;     // 4*NS
    float* ab    = qb;                 // alias: qb dead after attn_l1

    tanh_prep<<<2816, 256, 0, stream>>>(x, wq, wk, wv, xact, wqa, wka, wva);
    proj_l1<<<dim3(4, 64, 3), 256, 0, stream>>>(xact, wqa, wka, wva,
                                                gq, gk, gv, qb, kb, vb);
    attn_l1<<<dim3(16, 40), 256, 0, stream>>>(qb, kb, vb, gamma, rho, slabv, slabs);
    normalize_k<<<2048, 256, 0, stream>>>(slabv, slabs, ab);
    out_gemm<<<dim3(8, 32), 256, 0, stream>>>(ab, wo, wob, out);
}

// Round 8
// 636.011 us; speedup vs baseline: 1.8963x; 1.0027x over previous
//
#include <hip/hip_runtime.h>
#include <hip/hip_bf16.h>

#define T_SEQ 2048
#define CDIM 512
#define HDIM 8
#define DHEAD 64
#define BT 4096   // B*T

// ---------------------------------------------------------------------------
// Kernel 1: elementwise tanh of x and the three weight matrices
// ---------------------------------------------------------------------------
__global__ __launch_bounds__(256) void tanh_prep(
    const float* __restrict__ x,  const float* __restrict__ wq,
    const float* __restrict__ wk, const float* __restrict__ wv,
    float* __restrict__ xact, float* __restrict__ wqa,
    float* __restrict__ wka,  float* __restrict__ wva)
{
    const int NX = BT * CDIM / 4;     // 524288 float4
    const int NW = CDIM * CDIM / 4;   // 65536 float4
    int idx = blockIdx.x * 256 + threadIdx.x;
    const float4* src; float4* dst; int off;
    if (idx < NX)           { src = (const float4*)x;  dst = (float4*)xact; off = idx; }
    else if (idx < NX+NW)   { src = (const float4*)wq; dst = (float4*)wqa;  off = idx - NX; }
    else if (idx < NX+2*NW) { src = (const float4*)wk; dst = (float4*)wka;  off = idx - NX - NW; }
    else                    { src = (const float4*)wv; dst = (float4*)wva;  off = idx - NX - 2*NW; }
    float4 t = src[off];
    t.x = tanhf(t.x); t.y = tanhf(t.y); t.z = tanhf(t.z); t.w = tanhf(t.w);
    dst[off] = t;
}

// ---------------------------------------------------------------------------
// Kernel 2: L1-cdist projection. 64x128 tile, 256 threads, 4x8 micro-tile.
// ---------------------------------------------------------------------------
#define PSTR 36
__global__ __launch_bounds__(256) void proj_l1(
    const float* __restrict__ xact,
    const float* __restrict__ wqa, const float* __restrict__ wka, const float* __restrict__ wva,
    const float* __restrict__ gq,  const float* __restrict__ gk,  const float* __restrict__ gv,
    float* __restrict__ oq, float* __restrict__ okk, float* __restrict__ ov)
{
    __shared__ float As[64][PSTR];
    __shared__ float Bs[128][PSTR];

    const int z = blockIdx.z;
    const float* w    = (z == 0) ? wqa : (z == 1) ? wka : wva;
    const float* gain = (z == 0) ? gq  : (z == 1) ? gk  : gv;
    float* outp       = (z == 0) ? oq  : (z == 1) ? okk : ov;

    const int row0 = blockIdx.y * 64;
    const int col0 = blockIdx.x * 128;
    const int tid = threadIdx.x;
    const int tx = tid & 15, ty = tid >> 4;

    float acc[4][8];
    #pragma unroll
    for (int i = 0; i < 4; ++i)
        #pragma unroll
        for (int j = 0; j < 8; ++j) acc[i][j] = 0.f;

    for (int k0 = 0; k0 < CDIM; k0 += 32) {
        float4 av[2], bv[4];
        #pragma unroll
        for (int q = 0; q < 2; ++q) {
            const int fi = tid + 256 * q;
            av[q] = *(const float4*)&xact[(size_t)(row0 + (fi >> 3)) * CDIM + k0 + 4*(fi & 7)];
        }
        #pragma unroll
        for (int q = 0; q < 4; ++q) {
            const int fi = tid + 256 * q;
            bv[q] = *(const float4*)&w[(size_t)(col0 + (fi >> 3)) * CDIM + k0 + 4*(fi & 7)];
        }
        __syncthreads();
        #pragma unroll
        for (int q = 0; q < 2; ++q) {
            const int fi = tid + 256 * q;
            *(float4*)&As[fi >> 3][4*(fi & 7)] = av[q];
        }
        #pragma unroll
        for (int q = 0; q < 4; ++q) {
            const int fi = tid + 256 * q;
            *(float4*)&Bs[fi >> 3][4*(fi & 7)] = bv[q];
        }
        __syncthreads();

        #pragma unroll 2
        for (int kk = 0; kk < 32; kk += 4) {
            float4 a4[4], b4[8];
            #pragma unroll
            for (int i = 0; i < 4; ++i) a4[i] = *(const float4*)&As[ty + 16*i][kk];
            #pragma unroll
            for (int j = 0; j < 8; ++j) b4[j] = *(const float4*)&Bs[tx + 16*j][kk];
            #pragma unroll
            for (int i = 0; i < 4; ++i)
                #pragma unroll
                for (int j = 0; j < 8; ++j)
                    acc[i][j] += fabsf(a4[i].x - b4[j].x) + fabsf(a4[i].y - b4[j].y)
                               + fabsf(a4[i].z - b4[j].z) + fabsf(a4[i].w - b4[j].w);
        }
        __syncthreads();
    }

    float gcol[8];
    #pragma unroll
    for (int j = 0; j < 8; ++j) gcol[j] = gain[col0 + tx + 16*j];

    #pragma unroll
    for (int i = 0; i < 4; ++i) {
        const int r = row0 + ty + 16*i;
        #pragma unroll
        for (int j = 0; j < 8; ++j) {
            const int c = col0 + tx + 16*j;
            float val = (0.5f - acc[i][j] * (1.0f / 512.0f)) * gcol[j];
            if (z < 2) val = tanhf(val);
            outp[(size_t)r * CDIM + c] = val;
        }
    }
}

// ---------------------------------------------------------------------------
// Kernel 3: causal L1-kernel attention.
// Strip = 128 q-rows (Qs in LDS once). k-tile = 64 with W aliased onto Ks
// (K dead after scores) -> LDS 69 KB -> 2 blocks/CU (2 waves/SIMD).
// Next-tile K/V prefetched into registers (T14). 8x4 score micro-tile,
// PV in two 32-k halves through the KW union. Chunks of <=8 k-tiles ->
// 4 atomic-free slabs. Grid (16 bh, 40 slots), big strips first.
// NOTE: no min-waves launch_bounds hint — LDS already caps at 2 blocks/CU;
// the R7 ",2" hint clamped VGPRs (92) and spilled the prefetch state to
// scratch (WRITE_SIZE 23->97 MB). Let the allocator take ~160 VGPRs.
// ---------------------------------------------------------------------------
__global__ __launch_bounds__(256) void attn_l1(
    const float* __restrict__ qg, const float* __restrict__ kg, const float* __restrict__ vg,
    const float* __restrict__ gamma, const float* __restrict__ rho,
    float* __restrict__ slabv, float* __restrict__ slabs)
{
    __shared__ float Qs[128][68];
    __shared__ float Vs[64][68];
    __shared__ float KW[4608];   // union: Ks[64][68] (4352 f) / Ws[128][36] (4608 f)

    const int bh = blockIdx.x;
    const int b = bh >> 3, h = bh & 7;

    // decode slot -> (strip s, chunk c); big strips first
    int slot = blockIdx.y;
    int s = 15, c = 0;
    for (;; --s) {
        const int nc = (s >> 2) + 1;
        if (slot < nc) { c = slot; break; }
        slot -= nc;
    }
    const int i0 = s * 128;
    const int kt0 = 8 * c;
    const int kt1 = min(8 * c + 7, 2 * s + 1);

    const int tid = threadIdx.x;
    const int tx = tid & 15, ty = tid >> 4;

    const float gp = log1pf(__expf(gamma[h]));
    const float rp = log1pf(__expf(rho[h]));
    const float gp64 = gp * (1.0f / 64.0f);   // gp * 0.125^2
    const float mrho = -rp;

    const size_t hb = (size_t)b * T_SEQ * CDIM + h * DHEAD;

    // ---- load Q strip (128 x 64) into LDS ----
    {
        const int gr = tid >> 3;          // 0..31
        const int gc = (tid & 7) * 4;     // 0..28
        #pragma unroll
        for (int p = 0; p < 4; ++p)
            #pragma unroll
            for (int h2 = 0; h2 < 2; ++h2)
                *(float4*)&Qs[gr + 32*p][gc + 32*h2] =
                    *(const float4*)&qg[hb + (size_t)(i0 + gr + 32*p) * CDIM + gc + 32*h2];
    }

    // ---- prefetch first K/V tile (64 x 64 each; 4 float4 per thread each) ----
    float4 kpre[4], vpre[4];
    {
        const int j0 = kt0 * 64;
        #pragma unroll
        for (int q = 0; q < 4; ++q) {
            const int fi = tid + 256 * q;                 // 0..1023
            const size_t off = hb + (size_t)(j0 + (fi >> 4)) * CDIM + 4 * (fi & 15);
            kpre[q] = *(const float4*)&kg[off];
            vpre[q] = *(const float4*)&vg[off];
        }
    }

    float4 o4[8];
    float accs[8];
    float l1w[8][4];
    #pragma unroll
    for (int i = 0; i < 8; ++i) {
        o4[i] = make_float4(0.f, 0.f, 0.f, 0.f);
        accs[i] = 0.f;
    }

    for (int kt = kt0; kt <= kt1; ++kt) {
        __syncthreads();   // prev tile's PV2 done reading KW/Vs; Qs writes done
        {   // write staged K/V, then issue next tile's loads
            #pragma unroll
            for (int q = 0; q < 4; ++q) {
                const int fi = tid + 256 * q;
                const int r = fi >> 4, c4 = 4 * (fi & 15);
                *(float4*)&KW[r * 68 + c4] = kpre[q];
                *(float4*)&Vs[r][c4]       = vpre[q];
            }
            const int nkt = (kt + 1 <= kt1) ? kt + 1 : kt1;
            const int nj0 = nkt * 64;
            #pragma unroll
            for (int q = 0; q < 4; ++q) {
                const int fi = tid + 256 * q;
                const size_t off = hb + (size_t)(nj0 + (fi >> 4)) * CDIM + 4 * (fi & 15);
                kpre[q] = *(const float4*)&kg[off];
                vpre[q] = *(const float4*)&vg[off];
            }
        }
        __syncthreads();

        // ---- scores: L1 over d=64; q-rows ty+16i (i<8), k-rows tx+16j (j<4) ----
        #pragma unroll
        for (int i = 0; i < 8; ++i)
            #pragma unroll
            for (int j = 0; j < 4; ++j) l1w[i][j] = 0.f;

        #pragma unroll 2
        for (int d0 = 0; d0 < DHEAD; d0 += 4) {
            float4 a4[8];
            #pragma unroll
            for (int i = 0; i < 8; ++i) a4[i] = *(const float4*)&Qs[ty + 16*i][d0];
            #pragma unroll
            for (int j = 0; j < 4; ++j) {
                const float4 kx = *(const float4*)&KW[(tx + 16*j) * 68 + d0];
                #pragma unroll
                for (int i = 0; i < 8; ++i)
                    l1w[i][j] += fabsf(a4[i].x - kx.x) + fabsf(a4[i].y - kx.y)
                               + fabsf(a4[i].z - kx.z) + fabsf(a4[i].w - kx.w);
            }
        }

        // ---- kernel function + causal mask (diagonal tiles only) ----
        const int j0 = kt * 64;
        const bool diag = (kt >= 2 * s);
        #pragma unroll
        for (int i = 0; i < 8; ++i)
            #pragma unroll
            for (int j = 0; j < 4; ++j) {
                const float l1 = l1w[i][j];
                const float den = fmaf(gp64 * l1, l1, 1.000001f);
                float wgt = __builtin_amdgcn_exp2f(mrho * __builtin_amdgcn_logf(den));
                if (diag && (j0 + tx + 16*j) > (i0 + ty + 16*i)) wgt = 0.f;
                l1w[i][j] = wgt;
                accs[i] += wgt;
            }

        // ---- PV in two 32-k halves through the KW union (K now dead) ----
        #pragma unroll
        for (int hh = 0; hh < 2; ++hh) {
            __syncthreads();   // hh=0: K reads done; hh=1: PV1's W reads done
            #pragma unroll
            for (int i = 0; i < 8; ++i) {
                KW[(ty + 16*i) * 36 + tx]      = l1w[i][2*hh];
                KW[(ty + 16*i) * 36 + tx + 16] = l1w[i][2*hh + 1];
            }
            __syncthreads();

            #pragma unroll 2
            for (int jc = 0; jc < 32; jc += 4) {
                float4 w4[8], v4[4];
                #pragma unroll
                for (int i = 0; i < 8; ++i)
                    w4[i] = *(const float4*)&KW[(ty + 16*i) * 36 + jc];
                #pragma unroll
                for (int jj = 0; jj < 4; ++jj)
                    v4[jj] = *(const float4*)&Vs[32*hh + jc + jj][tx*4];
                #pragma unroll
                for (int i = 0; i < 8; ++i) {
                    o4[i].x += w4[i].x*v4[0].x + w4[i].y*v4[1].x + w4[i].z*v4[2].x + w4[i].w*v4[3].x;
                    o4[i].y += w4[i].x*v4[0].y + w4[i].y*v4[1].y + w4[i].z*v4[2].y + w4[i].w*v4[3].y;
                    o4[i].z += w4[i].x*v4[0].z + w4[i].y*v4[1].z + w4[i].z*v4[2].z + w4[i].w*v4[3].z;
                    o4[i].w += w4[i].x*v4[0].w + w4[i].y*v4[1].w + w4[i].z*v4[2].w + w4[i].w*v4[3].w;
                }
            }
        }
    }

    // ---- row-sum reduction over the 16 tx lanes (in-wave) ----
    #pragma unroll
    for (int i = 0; i < 8; ++i) {
        accs[i] += __shfl_xor(accs[i], 1, 64);
        accs[i] += __shfl_xor(accs[i], 2, 64);
        accs[i] += __shfl_xor(accs[i], 4, 64);
        accs[i] += __shfl_xor(accs[i], 8, 64);
    }

    // ---- store partials into this chunk's slab ----
    float* sv = slabv + (size_t)c * ((size_t)BT * CDIM);
    float* ss = slabs + (size_t)c * ((size_t)BT * HDIM);
    #pragma unroll
    for (int i = 0; i < 8; ++i) {
        const int qr = i0 + ty + 16*i;
        if (tx == 0)
            ss[(size_t)(b * T_SEQ + qr) * HDIM + h] = accs[i];
        *(float4*)&sv[hb + (size_t)qr * CDIM + tx*4] = o4[i];
    }
}

// ---------------------------------------------------------------------------
// Kernel 4: normalize: ab = (sum_c slabv[c]) / (sum_c slabs[c] + 1e-6),
// summing only chunks that exist for this row's strip (nch = s/4 + 1).
// ---------------------------------------------------------------------------
__global__ __launch_bounds__(256) void normalize_k(
    const float* __restrict__ slabv, const float* __restrict__ slabs,
    float* __restrict__ ab)
{
    int idx = blockIdx.x * 256 + threadIdx.x;   // < 524288 float4
    const int row = idx >> 7;          // 128 float4 per row of 512
    const int col = (idx & 127) << 2;
    const int h = col >> 6;
    const int t = row & (T_SEQ - 1);
    const int nch = ((t >> 7) >> 2) + 1;         // strip s = t/128; s/4 + 1

    const size_t NV = (size_t)BT * CDIM / 4;
    const size_t NS = (size_t)BT * HDIM;
    float4 v = ((const float4*)slabv)[idx];
    float ssum = slabs[(size_t)row * HDIM + h];
    #pragma unroll
    for (int c = 1; c < 4; ++c) {
        if (c < nch) {
            float4 u = ((const float4*)slabv)[c * NV + idx];
            v.x += u.x; v.y += u.y; v.z += u.z; v.w += u.w;
            ssum += slabs[c * NS + (size_t)row * HDIM + h];
        }
    }
    const float inv = 1.0f / (ssum + 1e-6f);
    v.x *= inv; v.y *= inv; v.z *= inv; v.w *= inv;
    ((float4*)ab)[idx] = v;
}

// ---------------------------------------------------------------------------
// Kernel 5: output projection Y = A @ wo^T + bias. M=4096, N=512, K=512.
// 128x64 tile, 8x4 micro. Grid (8, 32) = 256 blocks.
// ---------------------------------------------------------------------------
__global__ __launch_bounds__(256) void out_gemm(
    const float* __restrict__ A, const float* __restrict__ wo,
    const float* __restrict__ bias, float* __restrict__ Y)
{
    __shared__ float As[128][PSTR];
    __shared__ float Bs[64][PSTR];

    const int row0 = blockIdx.y * 128;
    const int col0 = blockIdx.x * 64;
    const int tid = threadIdx.x;
    const int tx = tid & 15, ty = tid >> 4;
    const int lr = tid >> 3;
    const int lc = (tid & 7) * 4;

    float acc[8][4];
    #pragma unroll
    for (int i = 0; i < 8; ++i)
        #pragma unroll
        for (int j = 0; j < 4; ++j) acc[i][j] = 0.f;

    for (int k0 = 0; k0 < CDIM; k0 += 32) {
        float4 ar[4];
        #pragma unroll
        for (int p = 0; p < 4; ++p)
            ar[p] = *(const float4*)&A[(size_t)(row0 + lr + 32*p) * CDIM + k0 + lc];
        float4 b0 = *(const float4*)&wo[(size_t)(col0 + lr)      * CDIM + k0 + lc];
        float4 b1 = *(const float4*)&wo[(size_t)(col0 + lr + 32) * CDIM + k0 + lc];
        __syncthreads();
        #pragma unroll
        for (int p = 0; p < 4; ++p)
            *(float4*)&As[lr + 32*p][lc] = ar[p];
        *(float4*)&Bs[lr][lc]      = b0;
        *(float4*)&Bs[lr + 32][lc] = b1;
        __syncthreads();

        #pragma unroll
        for (int kk = 0; kk < 32; kk += 4) {
            float4 a4[8], b4[4];
            #pragma unroll
            for (int i = 0; i < 8; ++i) a4[i] = *(const float4*)&As[ty + 16*i][kk];
            #pragma unroll
            for (int j = 0; j < 4; ++j) b4[j] = *(const float4*)&Bs[tx + 16*j][kk];
            #pragma unroll
            for (int i = 0; i < 8; ++i)
                #pragma unroll
                for (int j = 0; j < 4; ++j)
                    acc[i][j] += a4[i].x * b4[j].x + a4[i].y * b4[j].y
                               + a4[i].z * b4[j].z + a4[i].w * b4[j].w;
        }
    }

    float bcol[4];
    #pragma unroll
    for (int j = 0; j < 4; ++j) bcol[j] = bias[col0 + tx + 16*j];

    #pragma unroll
    for (int i = 0; i < 8; ++i) {
        const int r = row0 + ty + 16*i;
        #pragma unroll
        for (int j = 0; j < 4; ++j) {
            const int c = col0 + tx + 16*j;
            Y[(size_t)r * CDIM + c] = acc[i][j] + bcol[j];
        }
    }
}

// ---------------------------------------------------------------------------
extern "C" void kernel_launch(void* const* d_in, const int* in_sizes, int n_in,
                              void* d_out, int out_size, void* d_ws, size_t ws_size,
                              hipStream_t stream)
{
    (void)in_sizes; (void)n_in; (void)out_size; (void)ws_size;
    const float* x     = (const float*)d_in[0];
    // d_in[1] = mask (causal tril; semantics hardcoded)
    const float* wq    = (const float*)d_in[2];
    const float* gq    = (const float*)d_in[3];
    const float* wk    = (const float*)d_in[4];
    const float* gk    = (const float*)d_in[5];
    const float* wv    = (const float*)d_in[6];
    const float* gv    = (const float*)d_in[7];
    const float* wo    = (const float*)d_in[8];
    const float* wob   = (const float*)d_in[9];
    const float* gamma = (const float*)d_in[10];
    const float* rho   = (const float*)d_in[11];
    float* out = (float*)d_out;

    const size_t NV = (size_t)BT * CDIM;   // 2,097,152 floats
    const size_t NW = (size_t)CDIM * CDIM; //   262,144
    const size_t NS = (size_t)BT * HDIM;   //    32,768

    float* ws    = (float*)d_ws;
    float* xact  = ws;                 // NV
    float* wqa   = xact + NV;          // NW
    float* wka   = wqa + NW;
    float* wva   = wka + NW;
    float* qb    = wva + NW;           // NV
    float* kb    = qb + NV;
    float* vb    = kb + NV;
    float* slabv = vb + NV;            // 4*NV
    float* slabs = slabv + 4 * NV;     // 4*NS
    float* ab    = qb;                 // alias: qb dead after attn_l1

    tanh_prep<<<2816, 256, 0, stream>>>(x, wq, wk, wv, xact, wqa, wka, wva);
    proj_l1<<<dim3(4, 64, 3), 256, 0, stream>>>(xact, wqa, wka, wva,
                                                gq, gk, gv, qb, kb, vb);
    attn_l1<<<dim3(16, 40), 256, 0, stream>>>(qb, kb, vb, gamma, rho, slabv, slabs);
    normalize_k<<<2048, 256, 0, stream>>>(slabv, slabs, ab);
    out_gemm<<<dim3(8, 32), 256, 0, stream>>>(ab, wo, wob, out);
}